// Round 3
// baseline (493224.023 us; speedup 1.0000x reference)
//
#include <hip/hip_runtime.h>

#define HD 256
#define ID 32
#define OD 10
#define SEQ 512
#define NWG 16
#define BB 16
#define NLDS 37
#define NA 62
#define NV 20
#define SMEM_BYTES (8192 + 4 * NLDS * 1024)   // 159744 B (round-2-proven)

typedef __attribute__((ext_vector_type(4))) float f32x4;
typedef __attribute__((ext_vector_type(8))) unsigned short u16x8;
typedef __attribute__((ext_vector_type(8))) __bf16 bf16x8;

// ---- weight-fragment class map (per wave, lfid = ph*36 + g*9 + kt) --------
// class 3 = L2-streamed: {0..11} (ph0, window P) + {131..143} (ph3, window Q)
// class 2 = LDS-resident: {94..130} (37)
// class 1 = VGPR-resident: chain-end frags {17,26,35,44,53,62,71,80} + {81..92}
// class 0 = AGPR-resident (62) — fed to MFMA via inline asm "a" constraint
constexpr int wcls(int f) {
  if (f <= 11 || f >= 131) return 3;
  if (f >= 94 && f <= 130) return 2;
  if (f == 17 || f == 26 || f == 35 || f == 44 || f == 53 || f == 62 ||
      f == 71 || f == 80) return 1;
  if (f >= 81 && f <= 92) return 1;
  return 0;
}
constexpr int widx(int f) {
  int n = 0;
  for (int i = 0; i < f; ++i) n += (wcls(i) == wcls(f)) ? 1 : 0;
  return n;
}

static __device__ __forceinline__ unsigned short f2bf(float f) {
  unsigned u = __builtin_bit_cast(unsigned, f);
  u += 0x7fffu + ((u >> 16) & 1u);          // RNE
  return (unsigned short)(u >> 16);
}
static __device__ __forceinline__ float bf2f(unsigned short s) {
  unsigned u = ((unsigned)s) << 16;
  return __builtin_bit_cast(float, u);
}
static __device__ __forceinline__ f32x4 mfma16(u16x8 a, u16x8 b, f32x4 c) {
  return __builtin_amdgcn_mfma_f32_16x16x32_bf16(
      __builtin_bit_cast(bf16x8, a), __builtin_bit_cast(bf16x8, b), c, 0, 0, 0);
}
// AGPR-B MFMA, chain start: C = inline constant 0 (no VALU->MFMA srcC hazard)
static __device__ __forceinline__ f32x4 mfma_ag0(u16x8 a, const u16x8& b) {
  f32x4 d;
  asm("v_mfma_f32_16x16x32_bf16 %0, %1, %2, 0" : "=v"(d) : "v"(a), "a"(b));
  return d;
}
// AGPR-B MFMA, chain continue: MFMA->MFMA srcC accumulate (0 wait states)
static __device__ __forceinline__ void mfma_ag(f32x4& d, u16x8 a, const u16x8& b) {
  asm("v_mfma_f32_16x16x32_bf16 %0, %1, %2, %0" : "+v"(d) : "v"(a), "a"(b));
}
static __device__ __forceinline__ float fast_sigmoid(float x) {
  return 1.f / (1.f + __expf(-x));
}
static __device__ __forceinline__ float fast_tanh(float x) {
  return 1.f - 2.f / (__expf(2.f * x) + 1.f);
}

// ---------------------------------------------------------------------------
// Pack [Wx;Wh] (K=288 x N=1024 bf16) fragment-major (identical to round 2).
// f = w*144 + lfid, lfid = ph*36 + g*9 + kt; lane l slot i ->
//   B[k = 32*kt + 8*(l>>4) + i][j = 64w + 16ph + (l&15)]; 1KB per frag.
// ---------------------------------------------------------------------------
__global__ void pack_w(const float* __restrict__ Wgx, const float* __restrict__ Wgh,
                       const float* __restrict__ Wix, const float* __restrict__ Wih,
                       const float* __restrict__ Wfx, const float* __restrict__ Wfh,
                       const float* __restrict__ Wox, const float* __restrict__ Woh,
                       unsigned short* __restrict__ Wpk) {
  int p = blockIdx.x * blockDim.x + threadIdx.x;
  if (p >= 576 * 64) return;
  int f = p >> 6, l = p & 63;
  int w = f / 144, r = f % 144;
  int ph = r / 36, r2 = r % 36;
  int g = r2 / 9, kt = r2 % 9;
  int j = 64 * w + 16 * ph + (l & 15);
  const float* Wx[4] = {Wgx, Wix, Wfx, Wox};
  const float* Wh[4] = {Wgh, Wih, Wfh, Woh};
  u16x8 v;
  #pragma unroll
  for (int i = 0; i < 8; ++i) {
    int k = kt * 32 + 8 * (l >> 4) + i;
    float val = (k < ID) ? Wx[g][k * HD + j] : Wh[g][(k - ID) * HD + j];
    v[i] = f2bf(val);
  }
  *(u16x8*)(Wpk + ((size_t)f << 9) + (l << 3)) = v;
}

// ---------------------------------------------------------------------------
// Persistent recurrent kernel: 16 WGs x 256 threads (4 waves, 1/SIMD).
// Weights/wave: 62 frags AGPR + 20 VGPR + 37 LDS + 25 L2-streamed.
// ---------------------------------------------------------------------------
__global__ void __launch_bounds__(256, 1) lstm_rec(
    const float* __restrict__ x, const unsigned short* __restrict__ Wpk,
    const float* __restrict__ bgp, const float* __restrict__ bip,
    const float* __restrict__ bfp, const float* __restrict__ bop,
    const float* __restrict__ Wph, const float* __restrict__ bpp,
    float* __restrict__ out) {
  extern __shared__ __align__(16) unsigned char smem[];
  unsigned short* hbuf = (unsigned short*)smem;            // 16x256 bf16, swizzled
  unsigned short* wlds = (unsigned short*)(smem + 8192);   // 4*NLDS KB

  int tid = threadIdx.x;
  int w = tid >> 6, l = tid & 63;
  int l15 = l & 15, l4 = l >> 4;
  int b0 = blockIdx.x * BB;

  const unsigned short* wbase2 = Wpk + (((size_t)w * 144) << 9) + (l << 3);
  const size_t wldsofs = (size_t)w * NLDS * 512 + (l << 3);

  // ---- stage LDS-resident frags (global lfid 94..130 -> slot 0..36) ----
  #pragma unroll 1
  for (int f2 = 0; f2 < NLDS; ++f2) {
    u16x8 v = *(const u16x8*)(wbase2 + (((size_t)(94 + f2)) << 9));
    *(u16x8*)(wlds + wldsofs + ((size_t)f2 << 9)) = v;
  }
  // ---- zero h ----
  for (int idx = tid; idx < BB * HD; idx += 256) hbuf[idx] = 0;

  // ---- AGPR / VGPR / stream-P resident frags ----
  u16x8 wa[NA], wreg[NV], sbufP[12], sbufQ[13];
  #pragma unroll
  for (int f = 0; f < 144; ++f) {
    const int c = wcls(f), ix = widx(f);
    if (c == 2) continue;
    if (c == 3 && ix >= 12) continue;   // Q window loaded inside the loop
    u16x8 v = *(const u16x8*)(wbase2 + (((size_t)f) << 9));
    if (c == 0) wa[ix] = v;
    else if (c == 1) wreg[ix] = v;
    else sbufP[ix] = v;
  }

  // ---- biases ----
  float bias[4][4];
  {
    const float* bsrc[4] = {bgp, bip, bfp, bop};
    #pragma unroll
    for (int ph = 0; ph < 4; ++ph)
      #pragma unroll
      for (int g = 0; g < 4; ++g)
        bias[ph][g] = bsrc[g][64 * w + 16 * ph + l15];
  }
  float cst[4][4];
  #pragma unroll
  for (int ph = 0; ph < 4; ++ph)
    #pragma unroll
    for (int i = 0; i < 4; ++i) cst[ph][i] = 0.f;

  const float* xrow = x + ((size_t)(b0 + l15) * SEQ) * ID + 8 * l4;
  float4 xv0 = *(const float4*)(xrow);
  float4 xv1 = *(const float4*)(xrow + 4);

  __syncthreads();

  for (int t = 0; t < SEQ; ++t) {
    // ---- A fragments: a[0] = x_t; a[1..8] = h_{t-1} (swizzled LDS) ----
    u16x8 a[9];
    a[0][0] = f2bf(xv0.x); a[0][1] = f2bf(xv0.y); a[0][2] = f2bf(xv0.z); a[0][3] = f2bf(xv0.w);
    a[0][4] = f2bf(xv1.x); a[0][5] = f2bf(xv1.y); a[0][6] = f2bf(xv1.z); a[0][7] = f2bf(xv1.w);
    {
      int tn = (t + 1 < SEQ) ? (t + 1) : t;
      xv0 = *(const float4*)(xrow + (size_t)tn * ID);
      xv1 = *(const float4*)(xrow + (size_t)tn * ID + 4);
    }
    #pragma unroll
    for (int kt = 1; kt < 9; ++kt) {
      int cchunk = (kt - 1) * 4 + l4;
      int cs = cchunk ^ (l15 & 7);
      a[kt] = *(const u16x8*)(hbuf + l15 * HD + cs * 8);
    }
    __syncthreads();   // all waves done reading h_{t-1}

    #pragma unroll
    for (int ph = 0; ph < 4; ++ph) {
      f32x4 acc[4];
      #pragma unroll
      for (int g = 0; g < 4; ++g) {
        #pragma unroll
        for (int kt = 0; kt < 9; ++kt) {
          const int f = ph * 36 + g * 9 + kt;
          const int c = wcls(f);
          const int ix = widx(f);
          if (c == 0) {
            if (kt == 0) acc[g] = mfma_ag0(a[0], wa[ix]);
            else         mfma_ag(acc[g], a[kt], wa[ix]);
          } else {
            u16x8 bw;
            if (c == 1)      bw = wreg[ix];
            else if (c == 2) bw = *(const u16x8*)(wlds + wldsofs + ((size_t)ix << 9));
            else { if (ix < 12) bw = sbufP[ix]; else bw = sbufQ[ix - 12]; }
            if (kt == 0) acc[g] = mfma16(a[0], bw, f32x4{0.f, 0.f, 0.f, 0.f});
            else         acc[g] = mfma16(a[kt], bw, acc[g]);
          }
        }
      }
      if (ph == 1) {   // issue Q window (consumed late ph3): >=450 cy of cover
        #pragma unroll
        for (int q = 0; q < 13; ++q)
          sbufQ[q] = *(const u16x8*)(wbase2 + (((size_t)(131 + q)) << 9));
      }
      if (ph == 3) {   // re-issue P window for next step's ph0
        #pragma unroll
        for (int q = 0; q < 12; ++q)
          sbufP[q] = *(const u16x8*)(wbase2 + (((size_t)q) << 9));
      }
      // ---- gates for this phase's 16 cols; D: col=l15, row=4*l4+i ----
      #pragma unroll
      for (int i = 0; i < 4; ++i) {
        float gg = fast_tanh(acc[0][i] + bias[ph][0]);
        float ii = fast_sigmoid(acc[1][i] + bias[ph][1]);
        float ff = fast_sigmoid(acc[2][i] + bias[ph][2]);
        float oo = fast_sigmoid(acc[3][i] + bias[ph][3]);
        float cc = gg * ii + cst[ph][i] * ff;
        cst[ph][i] = cc;
        float hh = fast_tanh(cc) * oo;
        int row = 4 * l4 + i;
        int col = 64 * w + 16 * ph + l15;
        int ch = (col >> 3) ^ (row & 7);
        hbuf[row * HD + ch * 8 + (col & 7)] = f2bf(hh);
      }
    }
    __syncthreads();   // h_t complete
  }

  // ---- epilogue: logits = h @ Wph + bp, softmax ----
  float logit = 0.f;
  int eb = tid & 15, ej = tid >> 4;
  if (tid < 16 * OD) {
    float s = bpp[ej];
    for (int k = 0; k < HD; ++k) {
      int ch = (k >> 3) ^ (eb & 7);
      s += bf2f(hbuf[eb * HD + ch * 8 + (k & 7)]) * Wph[k * OD + ej];
    }
    logit = s;
  }
  __syncthreads();
  float* lbuf = (float*)smem;
  if (tid < 16 * OD) lbuf[eb * OD + ej] = logit;
  __syncthreads();
  if (tid < BB) {
    float m = -1e30f;
    #pragma unroll
    for (int j = 0; j < OD; ++j) m = fmaxf(m, lbuf[tid * OD + j]);
    float e[OD], sum = 0.f;
    #pragma unroll
    for (int j = 0; j < OD; ++j) { e[j] = __expf(lbuf[tid * OD + j] - m); sum += e[j]; }
    float inv = 1.f / sum;
    #pragma unroll
    for (int j = 0; j < OD; ++j) out[(b0 + tid) * OD + j] = e[j] * inv;
  }
}

extern "C" void kernel_launch(void* const* d_in, const int* in_sizes, int n_in,
                              void* d_out, int out_size, void* d_ws, size_t ws_size,
                              hipStream_t stream) {
  const float* X   = (const float*)d_in[0];
  const float* Wgx = (const float*)d_in[1];
  const float* Wgh = (const float*)d_in[2];
  const float* bg  = (const float*)d_in[3];
  const float* Wix = (const float*)d_in[4];
  const float* Wih = (const float*)d_in[5];
  const float* bi  = (const float*)d_in[6];
  const float* Wfx = (const float*)d_in[7];
  const float* Wfh = (const float*)d_in[8];
  const float* bf  = (const float*)d_in[9];
  const float* Wox = (const float*)d_in[10];
  const float* Woh = (const float*)d_in[11];
  const float* bo  = (const float*)d_in[12];
  const float* Wph = (const float*)d_in[13];
  const float* bp  = (const float*)d_in[14];
  unsigned short* Wpk = (unsigned short*)d_ws;  // 576 KB packed weights

  (void)hipFuncSetAttribute((const void*)lstm_rec,
                            hipFuncAttributeMaxDynamicSharedMemorySize,
                            SMEM_BYTES);

  pack_w<<<dim3(72), dim3(512), 0, stream>>>(Wgx, Wgh, Wix, Wih, Wfx, Wfh,
                                             Wox, Woh, Wpk);
  lstm_rec<<<dim3(NWG), dim3(256), SMEM_BYTES, stream>>>(
      X, Wpk, bg, bi, bf, bo, Wph, bp, (float*)d_out);
}

// Round 4
// 2973.558 us; speedup vs baseline: 165.8700x; 165.8700x over previous
//
#include <hip/hip_runtime.h>

#define HD 256
#define ID 32
#define OD 10
#define SEQ 512
#define NBG 16
#define FLAGS_OFF 589824            // after 576 KB packed weights
#define HX_OFF    622592            // after 32 KB flags
#define SMEM_BYTES (8192 + 65536)   // h double-buffer + 8 LDS frags x 8 waves

typedef __attribute__((ext_vector_type(4))) float f32x4;
typedef __attribute__((ext_vector_type(8))) unsigned short u16x8;
typedef __attribute__((ext_vector_type(8))) __bf16 bf16x8;
struct U2 { unsigned long long a, b; };

static __device__ __forceinline__ unsigned short f2bf(float f) {
  unsigned u = __builtin_bit_cast(unsigned, f);
  u += 0x7fffu + ((u >> 16) & 1u);          // RNE
  return (unsigned short)(u >> 16);
}
static __device__ __forceinline__ float bf2f(unsigned short s) {
  unsigned u = ((unsigned)s) << 16;
  return __builtin_bit_cast(float, u);
}
static __device__ __forceinline__ f32x4 mfma16(u16x8 a, u16x8 b, f32x4 c) {
  return __builtin_amdgcn_mfma_f32_16x16x32_bf16(
      __builtin_bit_cast(bf16x8, a), __builtin_bit_cast(bf16x8, b), c, 0, 0, 0);
}
static __device__ __forceinline__ float fast_sigmoid(float x) {
  return 1.f / (1.f + __expf(-x));
}
static __device__ __forceinline__ float fast_tanh(float x) {
  return 1.f - 2.f / (__expf(2.f * x) + 1.f);
}

// ---------------------------------------------------------------------------
// Pack weights fragment-major for the 32-WG geometry.
// hw = hf*8 + w (0..15), frag id f = hw*36 + g*9 + kt.
// lane l slot i -> W[k = 32kt + 8*(l>>4) + i][unit U = hw*16 + (l&15)] (gate g)
// ---------------------------------------------------------------------------
__global__ void pack_w(const float* __restrict__ Wgx, const float* __restrict__ Wgh,
                       const float* __restrict__ Wix, const float* __restrict__ Wih,
                       const float* __restrict__ Wfx, const float* __restrict__ Wfh,
                       const float* __restrict__ Wox, const float* __restrict__ Woh,
                       unsigned short* __restrict__ Wpk) {
  int p = blockIdx.x * blockDim.x + threadIdx.x;
  if (p >= 576 * 64) return;
  int f = p >> 6, l = p & 63;
  int hw = f / 36, r = f % 36;
  int g = r / 9, kt = r % 9;
  int U = hw * 16 + (l & 15);
  const float* Wx[4] = {Wgx, Wix, Wfx, Wox};
  const float* Wh[4] = {Wgh, Wih, Wfh, Woh};
  u16x8 v;
  #pragma unroll
  for (int i = 0; i < 8; ++i) {
    int k = kt * 32 + 8 * (l >> 4) + i;
    float val = (k < ID) ? Wx[g][k * HD + U] : Wh[g][(k - ID) * HD + U];
    v[i] = f2bf(val);
  }
  *(u16x8*)(Wpk + ((size_t)f << 9) + (l << 3)) = v;
}

// MFMA sequence, fully static indexing. Own-half kts first, partner kts last.
template <int HF>
static __device__ __forceinline__ void do_mfmas(
    const u16x8 (&wf)[4][7], const unsigned short* wlds_w, int l,
    const u16x8& ax, const u16x8 (&aown)[4], const u16x8 (&apart)[4],
    f32x4 (&acc)[4], bool full) {
  #pragma unroll
  for (int g = 0; g < 4; ++g) acc[g] = mfma16(ax, wf[g][0], acc[g]);
  if (!full) return;
  #pragma unroll
  for (int k2 = 0; k2 < 4; ++k2) {       // own half
    const int kt = 1 + 4 * HF + k2;
    #pragma unroll
    for (int g = 0; g < 4; ++g) {
      u16x8 bw;
      if (kt <= 6) bw = wf[g][kt];
      else bw = *(const u16x8*)(wlds_w + (g * 2 + (kt - 7)) * 512 + l * 8);
      acc[g] = mfma16(aown[k2], bw, acc[g]);
    }
  }
  #pragma unroll
  for (int k2 = 0; k2 < 4; ++k2) {       // partner half (late: loads in flight)
    const int kt = 1 + 4 * (1 - HF) + k2;
    #pragma unroll
    for (int g = 0; g < 4; ++g) {
      u16x8 bw;
      if (kt <= 6) bw = wf[g][kt];
      else bw = *(const u16x8*)(wlds_w + (g * 2 + (kt - 7)) * 512 + l * 8);
      acc[g] = mfma16(apart[k2], bw, acc[g]);
    }
  }
}

// ---------------------------------------------------------------------------
// 32 WGs = 16 batch-groups x 2 halves; 512 threads (8 waves, 2/SIMD).
// Weights resident (28 frags VGPR + 8 LDS per wave). Per-step h exchange
// between halves via device-scope atomics + step-indexed arrive flags.
// ---------------------------------------------------------------------------
__global__ void __launch_bounds__(512, 2) lstm_rec(
    const float* __restrict__ x, const unsigned short* __restrict__ Wpk,
    const float* __restrict__ bgp, const float* __restrict__ bip,
    const float* __restrict__ bfp, const float* __restrict__ bop,
    const float* __restrict__ Wph, const float* __restrict__ bpp,
    unsigned int* __restrict__ flags, void* __restrict__ hx,
    float* __restrict__ out) {
  extern __shared__ __align__(16) char smem[];
  unsigned short* hbuf = (unsigned short*)smem;            // [2][16][128] bf16
  unsigned short* wlds = (unsigned short*)(smem + 8192);   // [8 waves][8 frags][512]

  int tid = threadIdx.x;
  int w = tid >> 6, l = tid & 63;
  int l15 = l & 15, l4 = l >> 4;
  int bgi = blockIdx.x & 15, hf = blockIdx.x >> 4;
  int b0 = bgi * 16;
  char* hxc = (char*)hx;

  const unsigned short* wbase =
      Wpk + (((size_t)(hf * 8 + w) * 36) << 9) + (l << 3);
  unsigned short* wlds_w = wlds + w * 4096;

  // stage kt7,8 frags to LDS
  #pragma unroll
  for (int g = 0; g < 4; ++g)
    #pragma unroll
    for (int d = 0; d < 2; ++d) {
      u16x8 v = *(const u16x8*)(wbase + ((size_t)(g * 9 + 7 + d) << 9));
      *(u16x8*)(wlds_w + (g * 2 + d) * 512 + l * 8) = v;
    }
  // VGPR-resident frags (kt 0..6)
  u16x8 wf[4][7];
  #pragma unroll
  for (int g = 0; g < 4; ++g)
    #pragma unroll
    for (int kt = 0; kt < 7; ++kt)
      wf[g][kt] = *(const u16x8*)(wbase + ((size_t)(g * 9 + kt) << 9));

  float bias[4];
  {
    const float* bs[4] = {bgp, bip, bfp, bop};
    #pragma unroll
    for (int g = 0; g < 4; ++g) bias[g] = bs[g][hf * 128 + w * 16 + l15];
  }
  float cst[4] = {0.f, 0.f, 0.f, 0.f};

  const float* xrow = x + ((size_t)(b0 + l15) * SEQ) * ID + 8 * l4;
  float4 xv0 = *(const float4*)xrow;
  float4 xv1 = *(const float4*)(xrow + 4);

  __syncthreads();

  #pragma unroll 1
  for (int t = 0; t < SEQ; ++t) {
    u16x8 ax;
    ax[0] = f2bf(xv0.x); ax[1] = f2bf(xv0.y); ax[2] = f2bf(xv0.z); ax[3] = f2bf(xv0.w);
    ax[4] = f2bf(xv1.x); ax[5] = f2bf(xv1.y); ax[6] = f2bf(xv1.z); ax[7] = f2bf(xv1.w);
    {
      int tn = (t + 1 < SEQ) ? (t + 1) : t;
      xv0 = *(const float4*)(xrow + (size_t)tn * ID);
      xv1 = *(const float4*)(xrow + (size_t)tn * ID + 4);
    }

    u16x8 aown[4], apart[4];
    if (t > 0) {
      unsigned int* fprev = flags + (size_t)(t - 1) * NBG + bgi;
      while (__hip_atomic_load(fprev, __ATOMIC_ACQUIRE,
                               __HIP_MEMORY_SCOPE_AGENT) < 2u) {}
      // partner half: 8x8B coherent loads straight into A-fragments
      const unsigned long long* pp = (const unsigned long long*)
          (hxc + (size_t)((((t - 1) & 1) * NBG + bgi) * 2 + (1 - hf)) * 4096) +
          l15 * 32 + 2 * l4;
      #pragma unroll
      for (int k2 = 0; k2 < 4; ++k2) {
        unsigned long long v0 = __hip_atomic_load(pp + 8 * k2,
            __ATOMIC_RELAXED, __HIP_MEMORY_SCOPE_AGENT);
        unsigned long long v1 = __hip_atomic_load(pp + 8 * k2 + 1,
            __ATOMIC_RELAXED, __HIP_MEMORY_SCOPE_AGENT);
        U2 u{v0, v1};
        apart[k2] = __builtin_bit_cast(u16x8, u);
      }
      // own half from swizzled LDS
      const unsigned short* hb = hbuf + ((t - 1) & 1) * 2048 + l15 * 128;
      #pragma unroll
      for (int k2 = 0; k2 < 4; ++k2) {
        int c = 4 * k2 + l4;
        aown[k2] = *(const u16x8*)(hb + ((c ^ l15) & 15) * 8);
      }
    }

    f32x4 acc[4];
    #pragma unroll
    for (int g = 0; g < 4; ++g)
      acc[g] = f32x4{bias[g], bias[g], bias[g], bias[g]};
    if (hf == 0) do_mfmas<0>(wf, wlds_w, l, ax, aown, apart, acc, t > 0);
    else         do_mfmas<1>(wf, wlds_w, l, ax, aown, apart, acc, t > 0);

    // gates; D layout: col(unit)=l15, row(batch)=4*l4+i
    unsigned short* hw_ = hbuf + (t & 1) * 2048;
    unsigned int* hxo = (unsigned int*)
        (hxc + (size_t)(((t & 1) * NBG + bgi) * 2 + hf) * 4096);
    int ul = 16 * w + l15;
    #pragma unroll
    for (int i = 0; i < 4; ++i) {
      float gg = fast_tanh(acc[0][i]);
      float ii = fast_sigmoid(acc[1][i]);
      float ff = fast_sigmoid(acc[2][i]);
      float oo = fast_sigmoid(acc[3][i]);
      float cc = gg * ii + cst[i] * ff;
      cst[i] = cc;
      float hh = fast_tanh(cc) * oo;
      unsigned short me = f2bf(hh);
      int r = 4 * l4 + i;
      hw_[r * 128 + (((ul >> 3) ^ r) & 15) * 8 + (ul & 7)] = me;
      unsigned int ov = __shfl_xor((unsigned int)me, 1, 64);
      if ((l & 1) == 0) {
        unsigned int packed = (unsigned int)me | (ov << 16);
        __hip_atomic_store(hxo + r * 64 + (ul >> 1), packed,
                           __ATOMIC_RELAXED, __HIP_MEMORY_SCOPE_AGENT);
      }
    }
    __syncthreads();   // drains vmcnt: LDS h + published stores complete
    if (tid == 0)
      __hip_atomic_fetch_add(flags + (size_t)t * NBG + bgi, 1u,
                             __ATOMIC_RELEASE, __HIP_MEMORY_SCOPE_AGENT);
  }

  // ---- epilogue: half-0 WGs assemble full h, logits + softmax ----
  if (hf == 0) {
    unsigned int* flast = flags + (size_t)(SEQ - 1) * NBG + bgi;
    while (__hip_atomic_load(flast, __ATOMIC_ACQUIRE,
                             __HIP_MEMORY_SCOPE_AGENT) < 2u) {}
    unsigned long long* hfin = (unsigned long long*)wlds;  // [16][64] (weights dead)
    {
      int r = tid >> 5, c2 = tid & 31;
      int c = c2 >> 1, hq = c2 & 1;
      unsigned long long own = *(const unsigned long long*)
          (hbuf + 2048 + r * 128 + ((c ^ r) & 15) * 8 + hq * 4);
      const unsigned long long* pl = (const unsigned long long*)
          (hxc + (size_t)((1 * NBG + bgi) * 2 + 1) * 4096);
      unsigned long long pv = __hip_atomic_load(pl + tid, __ATOMIC_RELAXED,
                                                __HIP_MEMORY_SCOPE_AGENT);
      hfin[r * 64 + c2] = own;
      hfin[r * 64 + 32 + c2] = pv;
    }
    __syncthreads();
    const unsigned short* hfs = (const unsigned short*)hfin;
    float* lbuf = (float*)smem;       // reuse hbuf region (dead)
    if (tid < 16 * OD) {
      int eb = tid & 15, ej = tid >> 4;
      float s = bpp[ej];
      for (int k = 0; k < HD; ++k)
        s += bf2f(hfs[eb * 256 + k]) * Wph[k * OD + ej];
      lbuf[eb * OD + ej] = s;
    }
    __syncthreads();
    if (tid < 16) {
      float m = -1e30f;
      #pragma unroll
      for (int j = 0; j < OD; ++j) m = fmaxf(m, lbuf[tid * OD + j]);
      float e[OD], sum = 0.f;
      #pragma unroll
      for (int j = 0; j < OD; ++j) { e[j] = __expf(lbuf[tid * OD + j] - m); sum += e[j]; }
      float inv = 1.f / sum;
      #pragma unroll
      for (int j = 0; j < OD; ++j) out[(b0 + tid) * OD + j] = e[j] * inv;
    }
  }
}

extern "C" void kernel_launch(void* const* d_in, const int* in_sizes, int n_in,
                              void* d_out, int out_size, void* d_ws, size_t ws_size,
                              hipStream_t stream) {
  const float* X   = (const float*)d_in[0];
  const float* Wgx = (const float*)d_in[1];
  const float* Wgh = (const float*)d_in[2];
  const float* bg  = (const float*)d_in[3];
  const float* Wix = (const float*)d_in[4];
  const float* Wih = (const float*)d_in[5];
  const float* bi  = (const float*)d_in[6];
  const float* Wfx = (const float*)d_in[7];
  const float* Wfh = (const float*)d_in[8];
  const float* bf  = (const float*)d_in[9];
  const float* Wox = (const float*)d_in[10];
  const float* Woh = (const float*)d_in[11];
  const float* bo  = (const float*)d_in[12];
  const float* Wph = (const float*)d_in[13];
  const float* bp  = (const float*)d_in[14];

  unsigned short* Wpk   = (unsigned short*)d_ws;                       // 576 KB
  unsigned int*   flags = (unsigned int*)((char*)d_ws + FLAGS_OFF);    // 32 KB
  void*           hx    = (char*)d_ws + HX_OFF;                        // 256 KB

  hipMemsetAsync((char*)d_ws + FLAGS_OFF, 0, SEQ * NBG * 4, stream);
  (void)hipFuncSetAttribute((const void*)lstm_rec,
                            hipFuncAttributeMaxDynamicSharedMemorySize,
                            SMEM_BYTES);

  pack_w<<<dim3(72), dim3(512), 0, stream>>>(Wgx, Wgh, Wix, Wih, Wfx, Wfh,
                                             Wox, Woh, Wpk);
  lstm_rec<<<dim3(32), dim3(512), SMEM_BYTES, stream>>>(
      X, Wpk, bg, bi, bf, bo, Wph, bp, flags, hx, (float*)d_out);
}

// Round 5
// 1821.080 us; speedup vs baseline: 270.8414x; 1.6329x over previous
//
#include <hip/hip_runtime.h>

#define HD 256
#define ID 32
#define OD 10
#define SEQ 512
#define NBG 16
#define FLAGS_OFF 589824            // after 576 KB packed weights
#define HX_OFF    622592            // after flags
#define SMEM_BYTES (16384 + 65536)  // hbuf[2][16][256] + 8 waves x 8 LDS frags

typedef __attribute__((ext_vector_type(4))) float f32x4;
typedef __attribute__((ext_vector_type(8))) unsigned short u16x8;
typedef __attribute__((ext_vector_type(8))) __bf16 bf16x8;
struct U2 { unsigned long long a, b; };

static __device__ __forceinline__ unsigned short f2bf(float f) {
  unsigned u = __builtin_bit_cast(unsigned, f);
  u += 0x7fffu + ((u >> 16) & 1u);          // RNE
  return (unsigned short)(u >> 16);
}
static __device__ __forceinline__ float bf2f(unsigned short s) {
  unsigned u = ((unsigned)s) << 16;
  return __builtin_bit_cast(float, u);
}
static __device__ __forceinline__ f32x4 mfma16(u16x8 a, u16x8 b, f32x4 c) {
  return __builtin_amdgcn_mfma_f32_16x16x32_bf16(
      __builtin_bit_cast(bf16x8, a), __builtin_bit_cast(bf16x8, b), c, 0, 0, 0);
}
static __device__ __forceinline__ float fast_sigmoid(float x) {
  return 1.f / (1.f + __expf(-x));
}
static __device__ __forceinline__ float fast_tanh(float x) {
  return 1.f - 2.f / (__expf(2.f * x) + 1.f);
}

// ---------------------------------------------------------------------------
// Pack weights fragment-major (identical to round 4 geometry).
// hw = hf*8 + w (0..15), frag id f = hw*36 + g*9 + kt.
// lane l slot i -> W[k = 32kt + 8*(l>>4) + i][unit U = hw*16 + (l&15)] (gate g)
// kt=0 is exactly the x-block (k 0..31); kt=1..8 are h units 0..255.
// ---------------------------------------------------------------------------
__global__ void pack_w(const float* __restrict__ Wgx, const float* __restrict__ Wgh,
                       const float* __restrict__ Wix, const float* __restrict__ Wih,
                       const float* __restrict__ Wfx, const float* __restrict__ Wfh,
                       const float* __restrict__ Wox, const float* __restrict__ Woh,
                       unsigned short* __restrict__ Wpk) {
  int p = blockIdx.x * blockDim.x + threadIdx.x;
  if (p >= 576 * 64) return;
  int f = p >> 6, l = p & 63;
  int hw = f / 36, r = f % 36;
  int g = r / 9, kt = r % 9;
  int U = hw * 16 + (l & 15);
  const float* Wx[4] = {Wgx, Wix, Wfx, Wox};
  const float* Wh[4] = {Wgh, Wih, Wfh, Woh};
  u16x8 v;
  #pragma unroll
  for (int i = 0; i < 8; ++i) {
    int k = kt * 32 + 8 * (l >> 4) + i;
    float val = (k < ID) ? Wx[g][k * HD + U] : Wh[g][(k - ID) * HD + U];
    v[i] = f2bf(val);
  }
  *(u16x8*)(Wpk + ((size_t)f << 9) + (l << 3)) = v;
}

template <int HF>
static __device__ __forceinline__ void mfma_own(
    const u16x8 (&wf)[4][7], const unsigned short* wlds_w, int l,
    const u16x8& ax, const u16x8 (&aown)[4], f32x4 (&acc)[4], bool full) {
  #pragma unroll
  for (int g = 0; g < 4; ++g) acc[g] = mfma16(ax, wf[g][0], acc[g]);
  if (!full) return;
  #pragma unroll
  for (int k2 = 0; k2 < 4; ++k2) {
    const int kt = 1 + 4 * HF + k2;
    #pragma unroll
    for (int g = 0; g < 4; ++g) {
      u16x8 bw;
      if (kt <= 6) bw = wf[g][kt];
      else bw = *(const u16x8*)(wlds_w + (g * 2 + (kt - 7)) * 512 + l * 8);
      acc[g] = mfma16(aown[k2], bw, acc[g]);
    }
  }
}
template <int HF>
static __device__ __forceinline__ void mfma_part(
    const u16x8 (&wf)[4][7], const unsigned short* wlds_w, int l,
    const u16x8 (&apart)[4], f32x4 (&acc)[4]) {
  #pragma unroll
  for (int k2 = 0; k2 < 4; ++k2) {
    const int kt = 1 + 4 * (1 - HF) + k2;
    #pragma unroll
    for (int g = 0; g < 4; ++g) {
      u16x8 bw;
      if (kt <= 6) bw = wf[g][kt];
      else bw = *(const u16x8*)(wlds_w + (g * 2 + (kt - 7)) * 512 + l * 8);
      acc[g] = mfma16(apart[k2], bw, acc[g]);
    }
  }
}

// ---------------------------------------------------------------------------
// 32 WGs = 16 batch-groups x 2 hidden-halves; 512 threads (8 waves).
// Weights resident (28 VGPR/AGPR frags + 8 LDS frags per wave).
// Exchange: wave0-only poll (per-writer step-stamp flag) + wave0-only 4KB
// coherent load bounced through unified swizzled hbuf[2][16][256] in LDS.
// ---------------------------------------------------------------------------
__global__ void __launch_bounds__(512, 2) lstm_rec(
    const float* __restrict__ x, const unsigned short* __restrict__ Wpk,
    const float* __restrict__ bgp, const float* __restrict__ bip,
    const float* __restrict__ bfp, const float* __restrict__ bop,
    const float* __restrict__ Wph, const float* __restrict__ bpp,
    unsigned int* __restrict__ flags, void* __restrict__ hx,
    float* __restrict__ out) {
  extern __shared__ __align__(16) char smem[];
  unsigned short* hbuf = (unsigned short*)smem;            // [2][16][256] bf16
  unsigned short* wlds = (unsigned short*)(smem + 16384);  // [8][8*512]

  const int tid = threadIdx.x;
  const int w = tid >> 6, l = tid & 63;
  const int l15 = l & 15, l4 = l >> 4;
  const int bgi = blockIdx.x & 15, hf = blockIdx.x >> 4;
  const int b0 = bgi * 16;
  char* hxc = (char*)hx;
  unsigned int* myflag = flags + bgi * 2 + hf;
  unsigned int* pflag  = flags + bgi * 2 + (1 - hf);

  const unsigned short* wbase =
      Wpk + (((size_t)(hf * 8 + w) * 36) << 9) + (l << 3);
  unsigned short* wlds_w = wlds + w * 4096;

  // stage kt7,8 frags to LDS
  #pragma unroll
  for (int g = 0; g < 4; ++g)
    #pragma unroll
    for (int d = 0; d < 2; ++d) {
      u16x8 v = *(const u16x8*)(wbase + ((size_t)(g * 9 + 7 + d) << 9));
      *(u16x8*)(wlds_w + (g * 2 + d) * 512 + l * 8) = v;
    }
  // resident frags kt 0..6 (VGPR+AGPR)
  u16x8 wf[4][7];
  #pragma unroll
  for (int g = 0; g < 4; ++g)
    #pragma unroll
    for (int kt = 0; kt < 7; ++kt)
      wf[g][kt] = *(const u16x8*)(wbase + ((size_t)(g * 9 + kt) << 9));

  float bias[4];
  {
    const float* bs[4] = {bgp, bip, bfp, bop};
    #pragma unroll
    for (int g = 0; g < 4; ++g) bias[g] = bs[g][hf * 128 + w * 16 + l15];
  }
  float cst[4] = {0.f, 0.f, 0.f, 0.f};

  const float* xrow = x + ((size_t)(b0 + l15) * SEQ) * ID + 8 * l4;
  float4 xv0 = *(const float4*)xrow;
  float4 xv1 = *(const float4*)(xrow + 4);

  __syncthreads();

  #pragma unroll 1
  for (int t = 0; t < SEQ; ++t) {
    u16x8 ax;
    ax[0] = f2bf(xv0.x); ax[1] = f2bf(xv0.y); ax[2] = f2bf(xv0.z); ax[3] = f2bf(xv0.w);
    ax[4] = f2bf(xv1.x); ax[5] = f2bf(xv1.y); ax[6] = f2bf(xv1.z); ax[7] = f2bf(xv1.w);
    {
      int tn = (t + 1 < SEQ) ? (t + 1) : t;
      xv0 = *(const float4*)(xrow + (size_t)tn * ID);
      xv1 = *(const float4*)(xrow + (size_t)tn * ID + 4);
    }

    const int pr = (t - 1) & 1;          // parity holding h_{t-1}
    u16x8 aown[4];
    if (t > 0) {
      // own-half A-fragments from swizzled LDS
      const unsigned short* hb = hbuf + pr * 4096 + l15 * 256;
      #pragma unroll
      for (int k2 = 0; k2 < 4; ++k2) {
        int c = 4 * (4 * hf + k2) + l4;         // chunk of kt = 1+4*hf+k2
        aown[k2] = *(const u16x8*)(hb + ((c ^ l15) & 31) * 8);
      }
      if (w == 0) {
        // wave0: poll partner flag, fetch partner half, bounce into LDS
        while (__hip_atomic_load(pflag, __ATOMIC_ACQUIRE,
                                 __HIP_MEMORY_SCOPE_AGENT) < (unsigned)t) {}
        const unsigned long long* pp = (const unsigned long long*)
            (hxc + (size_t)((pr * NBG + bgi) * 2 + (1 - hf)) * 4096) + l * 8;
        unsigned long long d0[8];
        #pragma unroll
        for (int q = 0; q < 8; ++q)
          d0[q] = __hip_atomic_load(pp + q, __ATOMIC_RELAXED,
                                    __HIP_MEMORY_SCOPE_AGENT);
        int r = l >> 2;
        unsigned short* hw_ = hbuf + pr * 4096 + r * 256;
        #pragma unroll
        for (int q = 0; q < 4; ++q) {
          int gu = (1 - hf) * 128 + (l & 3) * 32 + q * 8;
          int ch = (gu >> 3) ^ r;
          U2 u{d0[2 * q], d0[2 * q + 1]};
          *(u16x8*)(hw_ + ch * 8) = __builtin_bit_cast(u16x8, u);
        }
      }
    }

    f32x4 acc[4];
    #pragma unroll
    for (int g = 0; g < 4; ++g)
      acc[g] = f32x4{bias[g], bias[g], bias[g], bias[g]};
    if (hf == 0) mfma_own<0>(wf, wlds_w, l, ax, aown, acc, t > 0);
    else         mfma_own<1>(wf, wlds_w, l, ax, aown, acc, t > 0);

    __syncthreads();   // B1: partner h in LDS, own MFMAs issued

    if (t > 0) {
      u16x8 apart[4];
      const unsigned short* hb = hbuf + pr * 4096 + l15 * 256;
      #pragma unroll
      for (int k2 = 0; k2 < 4; ++k2) {
        int c = 4 * (4 * (1 - hf) + k2) + l4;
        apart[k2] = *(const u16x8*)(hb + ((c ^ l15) & 31) * 8);
      }
      if (hf == 0) mfma_part<0>(wf, wlds_w, l, apart, acc);
      else         mfma_part<1>(wf, wlds_w, l, apart, acc);
    }

    // gates; D layout: col(unit)=l15, row(batch)=4*l4+i
    unsigned short* ho = hbuf + (t & 1) * 4096;
    unsigned int* hxo = (unsigned int*)
        (hxc + (size_t)(((t & 1) * NBG + bgi) * 2 + hf) * 4096);
    int ul = 16 * w + l15;
    #pragma unroll
    for (int i = 0; i < 4; ++i) {
      float gg = fast_tanh(acc[0][i]);
      float ii = fast_sigmoid(acc[1][i]);
      float ff = fast_sigmoid(acc[2][i]);
      float oo = fast_sigmoid(acc[3][i]);
      float cc = gg * ii + cst[i] * ff;
      cst[i] = cc;
      float hh = fast_tanh(cc) * oo;
      unsigned short me = f2bf(hh);
      int r = 4 * l4 + i;
      int gu = hf * 128 + ul;
      ho[r * 256 + (((gu >> 3) ^ r) & 31) * 8 + (gu & 7)] = me;
      unsigned int ov = __shfl_xor((unsigned int)me, 1, 64);
      if ((l & 1) == 0) {
        unsigned int packed = (unsigned int)me | (ov << 16);
        __hip_atomic_store(hxo + r * 64 + (ul >> 1), packed,
                           __ATOMIC_RELAXED, __HIP_MEMORY_SCOPE_AGENT);
      }
    }
    __syncthreads();   // B2: all LDS + hx stores drained
    if (tid == 0)
      __hip_atomic_store(myflag, (unsigned)(t + 1), __ATOMIC_RELEASE,
                         __HIP_MEMORY_SCOPE_AGENT);
  }

  // ---- epilogue: half-0 fetches partner h_511, logits + softmax ----
  if (hf == 0) {
    if (w == 0) {
      while (__hip_atomic_load(pflag, __ATOMIC_ACQUIRE,
                               __HIP_MEMORY_SCOPE_AGENT) < (unsigned)SEQ) {}
      const unsigned long long* pp = (const unsigned long long*)
          (hxc + (size_t)((1 * NBG + bgi) * 2 + 1) * 4096) + l * 8;
      unsigned long long d0[8];
      #pragma unroll
      for (int q = 0; q < 8; ++q)
        d0[q] = __hip_atomic_load(pp + q, __ATOMIC_RELAXED,
                                  __HIP_MEMORY_SCOPE_AGENT);
      int r = l >> 2;
      unsigned short* hw_ = hbuf + 4096 + r * 256;
      #pragma unroll
      for (int q = 0; q < 4; ++q) {
        int gu = 128 + (l & 3) * 32 + q * 8;
        int ch = (gu >> 3) ^ r;
        U2 u{d0[2 * q], d0[2 * q + 1]};
        *(u16x8*)(hw_ + ch * 8) = __builtin_bit_cast(u16x8, u);
      }
    }
    __syncthreads();
    float* lbuf = (float*)(smem + 16384);   // weights LDS dead now
    if (tid < 16 * OD) {
      int eb = tid & 15, ej = tid >> 4;
      float s = bpp[ej];
      for (int k = 0; k < HD; ++k)
        s += bf2f(hbuf[4096 + eb * 256 + (((k >> 3) ^ eb) & 31) * 8 + (k & 7)]) *
             Wph[k * OD + ej];
      lbuf[eb * OD + ej] = s;
    }
    __syncthreads();
    if (tid < 16) {
      float m = -1e30f;
      #pragma unroll
      for (int j = 0; j < OD; ++j) m = fmaxf(m, lbuf[tid * OD + j]);
      float e[OD], sum = 0.f;
      #pragma unroll
      for (int j = 0; j < OD; ++j) { e[j] = __expf(lbuf[tid * OD + j] - m); sum += e[j]; }
      float inv = 1.f / sum;
      #pragma unroll
      for (int j = 0; j < OD; ++j) out[(b0 + tid) * OD + j] = e[j] * inv;
    }
  }
}

extern "C" void kernel_launch(void* const* d_in, const int* in_sizes, int n_in,
                              void* d_out, int out_size, void* d_ws, size_t ws_size,
                              hipStream_t stream) {
  const float* X   = (const float*)d_in[0];
  const float* Wgx = (const float*)d_in[1];
  const float* Wgh = (const float*)d_in[2];
  const float* bg  = (const float*)d_in[3];
  const float* Wix = (const float*)d_in[4];
  const float* Wih = (const float*)d_in[5];
  const float* bi  = (const float*)d_in[6];
  const float* Wfx = (const float*)d_in[7];
  const float* Wfh = (const float*)d_in[8];
  const float* bf  = (const float*)d_in[9];
  const float* Wox = (const float*)d_in[10];
  const float* Woh = (const float*)d_in[11];
  const float* bo  = (const float*)d_in[12];
  const float* Wph = (const float*)d_in[13];
  const float* bp  = (const float*)d_in[14];

  unsigned short* Wpk   = (unsigned short*)d_ws;                     // 576 KB
  unsigned int*   flags = (unsigned int*)((char*)d_ws + FLAGS_OFF);  // 128 B
  void*           hx    = (char*)d_ws + HX_OFF;                      // 256 KB

  hipMemsetAsync((char*)d_ws + FLAGS_OFF, 0, 32 * 4, stream);
  (void)hipFuncSetAttribute((const void*)lstm_rec,
                            hipFuncAttributeMaxDynamicSharedMemorySize,
                            SMEM_BYTES);

  pack_w<<<dim3(72), dim3(512), 0, stream>>>(Wgx, Wgh, Wix, Wih, Wfx, Wfh,
                                             Wox, Woh, Wpk);
  lstm_rec<<<dim3(32), dim3(512), SMEM_BYTES, stream>>>(
      X, Wpk, bg, bi, bf, bo, Wph, bp, flags, hx, (float*)d_out);
}